// Round 10
// baseline (433.300 us; speedup 1.0000x reference)
//
#include <hip/hip_runtime.h>

#define HH 512
#define WW 512
#define BB 4
#define SH 64
#define SW 64
#define NSUP 64          // 64 super-steps x 2 iters = 128
#define LAMV 0.24f
#define EPSV 1e-8f

// strip slot: 576 u32 per (edge,b,tY,tX); edge 0=Top(rows0..8),1=Bot(rows55..63),
// 2=Lft(cols0..8),3=Rgt(cols55..63). Row strips: word=r*64+c; col strips: word=c*64+r.
// tag bits in mantissa: bit0=1 (anti-poison: 0xAA.. and final-image stores have bit0=0),
// bit1=phase=(S>>1)&1. Parity (S&1) picks halo0/halo1 -> reuse distance 4 supers, and
// skew<=1 induction makes overwrite-before-read impossible.
#define SLOT(e, bb, tY, tX) (((((e) * BB + (bb)) * 64 + (tY) * 8 + (tX))) * 576)

__device__ __forceinline__ void st32(unsigned* p, unsigned v) {
    __hip_atomic_store(p, v, __ATOMIC_RELAXED, __HIP_MEMORY_SCOPE_AGENT);
}
__device__ __forceinline__ unsigned ld32(unsigned* p) {
    return __hip_atomic_load(p, __ATOMIC_RELAXED, __HIP_MEMORY_SCOPE_AGENT);
}

// ---------------- prep: cv / ch edge weights (unchanged, verified) ----------------
__global__ __launch_bounds__(256) void prep_kernel(
    const float* __restrict__ image, const float* __restrict__ ybic,
    const float* __restrict__ logk,
    float* __restrict__ cv, float* __restrict__ ch)
{
    int idx = blockIdx.x * 256 + threadIdx.x;
    if (idx >= BB * HH * WW) return;
    int x = idx % WW;
    int y = (idx / WW) % HH;
    int b = idx / (WW * HH);

    float K = expf(logk[0]);
    float invK2 = 1.0f / (K * K);

    const float* img = image + (size_t)b * 3 * HH * WW;
    const float* yb  = ybic  + (size_t)b * HH * WW;

    float f0 = img[y * WW + x];
    float f1 = img[HH * WW + y * WW + x];
    float f2 = img[2 * HH * WW + y * WW + x];
    float f3 = yb[y * WW + x];

    if (y < HH - 1) {
        float s = fabsf(img[(y + 1) * WW + x] - f0)
                + fabsf(img[HH * WW + (y + 1) * WW + x] - f1)
                + fabsf(img[2 * HH * WW + (y + 1) * WW + x] - f2)
                + fabsf(yb[(y + 1) * WW + x] - f3);
        s *= 0.25f;
        cv[(size_t)b * (HH - 1) * WW + y * WW + x] = 1.0f / (1.0f + s * s * invK2);
    }
    if (x < WW - 1) {
        float s = fabsf(img[y * WW + x + 1] - f0)
                + fabsf(img[HH * WW + y * WW + x + 1] - f1)
                + fabsf(img[2 * HH * WW + y * WW + x + 1] - f2)
                + fabsf(yb[y * WW + x + 1] - f3);
        s *= 0.25f;
        ch[(size_t)b * HH * (WW - 1) + y * (WW - 1) + x] = 1.0f / (1.0f + s * s * invK2);
    }
}

// ---------------- persistent T=2 kernel ----------------
__global__ __launch_bounds__(256) void persist_kernel(
    const float* __restrict__ ybic, float* out_img,
    const float* __restrict__ cv, const float* __restrict__ ch,
    const float* __restrict__ src, const float* __restrict__ mask,
    unsigned* halo0, unsigned* __restrict__ halo1, int* __restrict__ cnt)
{
    const int b = blockIdx.z, tY = blockIdx.y, tX = blockIdx.x;
    const int tid = threadIdx.x;
    const int tx = tid & 15, ty = tid >> 4;
    const int w = tid >> 6, l = tid & 63;
    const int y0 = tY * 64 + ty * 4, x0 = tX * 64 + tx * 4;
    const bool eT = tY > 0, eB = tY < 7, eL = tX > 0, eR = tX < 7;

    const float* cvb = cv + (size_t)b * (HH - 1) * WW;
    const float* chb = ch + (size_t)b * HH * (WW - 1);

    // ---- main state + coeffs (verified math) ----
    float I[4][4];
    #pragma unroll
    for (int r = 0; r < 4; ++r) {
        float4 t = *(const float4*)(ybic + ((size_t)b * HH + y0 + r) * WW + x0);
        I[r][0] = t.x; I[r][1] = t.y; I[r][2] = t.z; I[r][3] = t.w;
    }
    float cvaL[5][4];
    #pragma unroll
    for (int i = 0; i < 5; ++i) {
        int y = y0 - 1 + i;
        if (y >= 0 && y < HH - 1) {
            float4 t = *(const float4*)(cvb + (size_t)y * WW + x0);
            cvaL[i][0] = t.x * LAMV; cvaL[i][1] = t.y * LAMV;
            cvaL[i][2] = t.z * LAMV; cvaL[i][3] = t.w * LAMV;
        } else {
            #pragma unroll
            for (int c = 0; c < 4; ++c) cvaL[i][c] = 0.0f;
        }
    }
    float chaL[4][5];
    #pragma unroll
    for (int r = 0; r < 4; ++r) {
        const float* row = chb + (size_t)(y0 + r) * (WW - 1);
        #pragma unroll
        for (int j = 0; j < 5; ++j) {
            int x = x0 - 1 + j;
            chaL[r][j] = ((unsigned)x <= (unsigned)(WW - 2)) ? row[x] * LAMV : 0.0f;
        }
    }
    const size_t sidx = ((size_t)b * SH + (y0 >> 3)) * SW + (x0 >> 3);
    const float sv = src[sidx];
    const bool useR = (mask[sidx] >= 0.5f);

    // ---- strip role coeffs (wave w: 0=T,1=B,2=L,3=R; lane l = col/row) ----
    const bool sEx = (w == 0) ? eT : (w == 1) ? eB : (w == 2) ? eL : eR;
    float sA[9];
    float sB[8][2];
    float svS = 0.0f; bool useRS = false;
    #pragma unroll
    for (int i = 0; i < 9; ++i) sA[i] = 0.0f;
    #pragma unroll
    for (int i = 0; i < 8; ++i) { sB[i][0] = 0.0f; sB[i][1] = 0.0f; }
    if (sEx) {
        if (w == 0) {                      // top strip: col gx, rows Y0-8..-1
            int gx = tX * 64 + l;
            #pragma unroll
            for (int i = 0; i < 9; ++i) sA[i] = cvb[(size_t)(tY * 64 - 9 + i) * WW + gx] * LAMV;
            #pragma unroll
            for (int i = 0; i < 8; ++i) {
                int gr = tY * 64 - 8 + i;
                sB[i][0] = (gx >= 1)      ? chb[(size_t)gr * (WW - 1) + gx - 1] * LAMV : 0.0f;
                sB[i][1] = (gx <= WW - 2) ? chb[(size_t)gr * (WW - 1) + gx]     * LAMV : 0.0f;
            }
            size_t s2 = ((size_t)b * SH + (tY * 8 - 1)) * SW + tX * 8 + (l >> 3);
            svS = src[s2]; useRS = (mask[s2] >= 0.5f);
        } else if (w == 1) {               // bottom strip: col gx, rows Y0+64..71
            int gx = tX * 64 + l;
            #pragma unroll
            for (int i = 0; i < 9; ++i) sA[i] = cvb[(size_t)(tY * 64 + 63 + i) * WW + gx] * LAMV;
            #pragma unroll
            for (int i = 0; i < 8; ++i) {
                int gr = tY * 64 + 64 + i;
                sB[i][0] = (gx >= 1)      ? chb[(size_t)gr * (WW - 1) + gx - 1] * LAMV : 0.0f;
                sB[i][1] = (gx <= WW - 2) ? chb[(size_t)gr * (WW - 1) + gx]     * LAMV : 0.0f;
            }
            size_t s2 = ((size_t)b * SH + (tY * 8 + 8)) * SW + tX * 8 + (l >> 3);
            svS = src[s2]; useRS = (mask[s2] >= 0.5f);
        } else if (w == 2) {               // left strip: row gr, cols X0-8..-1
            int gr = tY * 64 + l;
            #pragma unroll
            for (int i = 0; i < 9; ++i) sA[i] = chb[(size_t)gr * (WW - 1) + tX * 64 - 9 + i] * LAMV;
            #pragma unroll
            for (int j = 0; j < 8; ++j) {
                int gc = tX * 64 - 8 + j;
                sB[j][0] = (gr >= 1)      ? cvb[(size_t)(gr - 1) * WW + gc] * LAMV : 0.0f;
                sB[j][1] = (gr <= HH - 2) ? cvb[(size_t)gr * WW + gc]       * LAMV : 0.0f;
            }
            size_t s2 = ((size_t)b * SH + (tY * 8 + (l >> 3))) * SW + tX * 8 - 1;
            svS = src[s2]; useRS = (mask[s2] >= 0.5f);
        } else {                           // right strip: row gr, cols X0+64..71
            int gr = tY * 64 + l;
            #pragma unroll
            for (int i = 0; i < 9; ++i) sA[i] = chb[(size_t)gr * (WW - 1) + tX * 64 + 63 + i] * LAMV;
            #pragma unroll
            for (int j = 0; j < 8; ++j) {
                int gc = tX * 64 + 64 + j;
                sB[j][0] = (gr >= 1)      ? cvb[(size_t)(gr - 1) * WW + gc] * LAMV : 0.0f;
                sB[j][1] = (gr <= HH - 2) ? cvb[(size_t)gr * WW + gc]       * LAMV : 0.0f;
            }
            size_t s2 = ((size_t)b * SH + (tY * 8 + (l >> 3))) * SW + tX * 8 + 8;
            svS = src[s2]; useRS = (mask[s2] >= 0.5f);
        }
    }

    // ---- poll word decode: up to 10 slots/thread; packed offs(20b)|lofs(12b) ----
    unsigned pk[10];
    unsigned pend0 = 0;
    #pragma unroll
    for (int q = 0; q < 10; ++q) {
        int g = tid + q * 256;
        unsigned offs = 0; int lofs = 0; bool act = false;
        if (g < 2304) {
            int e = g / 576, wi = g % 576;
            int sy = tY, sx = tX, ep = 0;
            if (e == 0)      { ep = 1; act = eT; if (act) sy = tY - 1; }
            else if (e == 1) { ep = 0; act = eB; if (act) sy = tY + 1; }
            else if (e == 2) { ep = 3; act = eL; if (act) sx = tX - 1; }
            else             { ep = 2; act = eR; if (act) sx = tX + 1; }
            offs = SLOT(ep, b, sy, sx) + wi;
            lofs = e * 576 + wi;
        } else if (g < 2368) {
            int q2 = g - 2304, corner = q2 >> 4, j = q2 & 15, jj = j & 7;
            bool vp = (j < 8);
            int dy = (corner < 2) ? -1 : 1, dx = (corner & 1) ? 1 : -1;
            act = ((dy < 0) ? eT : eB) && ((dx < 0) ? eL : eR);
            int sy = act ? tY + dy : tY, sx = act ? tX + dx : tX;
            int ep, wi;
            if (vp) { ep = (dx < 0) ? 3 : 2; wi = ((dx < 0) ? 8 : 0) * 64 + ((dy < 0) ? 56 + jj : jj); }
            else    { ep = (dy < 0) ? 1 : 0; wi = ((dy < 0) ? 8 : 0) * 64 + ((dx < 0) ? 56 + jj : jj); }
            offs = SLOT(ep, b, sy, sx) + wi;
            lofs = 2304 + corner * 16 + j;
        }
        pk[q] = offs | ((unsigned)lofs << 20);
        if (act) pend0 |= (1u << q);
    }

    // ---- LDS ----
    __shared__ float pollLDS[2368];                 // raw strips 4x576 + corners 4x16
    __shared__ float topE[2][16][16][4];
    __shared__ float botE[2][16][16][4];
    __shared__ float lftE[2][16][16][4];
    __shared__ float rgtE[2][16][16][4];
    __shared__ float ringT[64], ringB[64], ringL[64], ringR[64];

    #pragma unroll
    for (int q = 0; q < 10; ++q) {
        int g = tid + q * 256;
        if (g < 2368) pollLDS[g] = 0.0f;
    }
    __syncthreads();

    #pragma unroll 1
    for (int S = 0; S < NSUP; ++S) {
        const int p = S & 1;
        const unsigned phase = ((unsigned)S >> 1) & 1u;
        const unsigned tagOr = 1u | (phase << 1);
        unsigned* hb = p ? halo1 : halo0;

        // ---- phase 0: publish strips (tagged u32) + LDS edges + poll ----
        if (eT && ty <= 2) {
            unsigned base = SLOT(0, b, tY, tX);
            #pragma unroll
            for (int i = 0; i < 4; ++i) {
                int r = ty * 4 + i;
                if (r <= 8) {
                    #pragma unroll
                    for (int c = 0; c < 4; ++c)
                        st32(hb + base + r * 64 + tx * 4 + c, (__float_as_uint(I[i][c]) & ~3u) | tagOr);
                }
            }
        }
        if (eB && ty >= 13) {
            unsigned base = SLOT(1, b, tY, tX);
            #pragma unroll
            for (int i = 0; i < 4; ++i) {
                int rs = ty * 4 + i - 55;
                if (rs >= 0) {
                    #pragma unroll
                    for (int c = 0; c < 4; ++c)
                        st32(hb + base + rs * 64 + tx * 4 + c, (__float_as_uint(I[i][c]) & ~3u) | tagOr);
                }
            }
        }
        if (eL && tx <= 2) {
            unsigned base = SLOT(2, b, tY, tX);
            #pragma unroll
            for (int j = 0; j < 4; ++j) {
                int cc = tx * 4 + j;
                if (cc <= 8) {
                    #pragma unroll
                    for (int i = 0; i < 4; ++i)
                        st32(hb + base + cc * 64 + ty * 4 + i, (__float_as_uint(I[i][j]) & ~3u) | tagOr);
                }
            }
        }
        if (eR && tx >= 13) {
            unsigned base = SLOT(3, b, tY, tX);
            #pragma unroll
            for (int j = 0; j < 4; ++j) {
                int cs = tx * 4 + j - 55;
                if (cs >= 0) {
                    #pragma unroll
                    for (int i = 0; i < 4; ++i)
                        st32(hb + base + cs * 64 + ty * 4 + i, (__float_as_uint(I[i][j]) & ~3u) | tagOr);
                }
            }
        }
        #pragma unroll
        for (int c = 0; c < 4; ++c) {
            topE[0][ty][tx][c] = I[0][c];
            botE[0][ty][tx][c] = I[3][c];
            lftE[0][ty][tx][c] = I[c][0];
            rgtE[0][ty][tx][c] = I[c][3];
        }

        unsigned pd = pend0;
        while (pd) {
            unsigned got = 0;
            #pragma unroll
            for (int q = 0; q < 10; ++q) {
                if (pd & (1u << q)) {
                    unsigned wv = ld32(hb + (pk[q] & 0xFFFFFu));
                    if ((wv & 3u) == tagOr) { pollLDS[pk[q] >> 20] = __uint_as_float(wv); got |= (1u << q); }
                }
            }
            pd &= ~got;
        }
        __syncthreads();   // bar1: raw strips + edges p0 complete

        // ---- phase 1: step A (iter 2S -> 2S+1) ----
        float I1[4][4];
        {
            float up[4], dn[4], lf[4], rg[4];
            if (ty > 0) {
                #pragma unroll
                for (int c = 0; c < 4; ++c) up[c] = botE[0][ty - 1][tx][c];
            } else if (eT) {
                #pragma unroll
                for (int c = 0; c < 4; ++c) up[c] = pollLDS[8 * 64 + tx * 4 + c];
            } else { up[0] = up[1] = up[2] = up[3] = 0.0f; }
            if (ty < 15) {
                #pragma unroll
                for (int c = 0; c < 4; ++c) dn[c] = topE[0][ty + 1][tx][c];
            } else if (eB) {
                #pragma unroll
                for (int c = 0; c < 4; ++c) dn[c] = pollLDS[576 + tx * 4 + c];
            } else { dn[0] = dn[1] = dn[2] = dn[3] = 0.0f; }
            if (tx > 0) {
                #pragma unroll
                for (int r = 0; r < 4; ++r) lf[r] = rgtE[0][ty][tx - 1][r];
            } else if (eL) {
                #pragma unroll
                for (int r = 0; r < 4; ++r) lf[r] = pollLDS[1152 + 8 * 64 + ty * 4 + r];
            } else { lf[0] = lf[1] = lf[2] = lf[3] = 0.0f; }
            if (tx < 15) {
                #pragma unroll
                for (int r = 0; r < 4; ++r) rg[r] = lftE[0][ty][tx + 1][r];
            } else if (eR) {
                #pragma unroll
                for (int r = 0; r < 4; ++r) rg[r] = pollLDS[1728 + ty * 4 + r];
            } else { rg[0] = rg[1] = rg[2] = rg[3] = 0.0f; }

            float s = 0.0f;
            #pragma unroll
            for (int r = 0; r < 4; ++r) {
                #pragma unroll
                for (int c = 0; c < 4; ++c) {
                    const float v = I[r][c];
                    const float u = r       ? I[r - 1][c] : up[c];
                    const float d = (r < 3) ? I[r + 1][c] : dn[c];
                    const float le = c      ? I[r][c - 1] : lf[r];
                    const float ri = (c < 3) ? I[r][c + 1] : rg[r];
                    const float t = cvaL[r + 1][c] * (d - v) - cvaL[r][c] * (v - u)
                                  + chaL[r][c + 1] * (ri - v) - chaL[r][c] * (v - le);
                    const float nw = v + t;
                    I1[r][c] = nw; s += nw;
                }
            }
            s += __shfl_xor(s, 1);
            s += __shfl_xor(s, 16);
            const float ratio = useR ? (sv / (s * (1.0f / 64.0f) + EPSV)) : 1.0f;
            #pragma unroll
            for (int r = 0; r < 4; ++r) {
                #pragma unroll
                for (int c = 0; c < 4; ++c) I1[r][c] *= ratio;
            }
        }
        #pragma unroll
        for (int c = 0; c < 4; ++c) {
            topE[1][ty][tx][c] = I1[0][c];
            botE[1][ty][tx][c] = I1[3][c];
            lftE[1][ty][tx][c] = I1[c][0];
            rgtE[1][ty][tx][c] = I1[c][3];
        }

        // strip step A (halo blocks), ring value -> LDS
        if (sEx) {
            float sI[8], nv[8];
            float s = 0.0f;
            if (w == 0) {          // top: rows -8..-1, col l
                #pragma unroll
                for (int i = 0; i < 8; ++i) sI[i] = pollLDS[(1 + i) * 64 + l];
                const float upr = pollLDS[l];
                const float dnr = topE[0][0][l >> 2][l & 3];
                #pragma unroll
                for (int i = 0; i < 8; ++i) {
                    const float v = sI[i];
                    const float u = i ? sI[i - 1] : upr;
                    const float d = (i < 7) ? sI[i + 1] : dnr;
                    const float le = (l > 0)  ? pollLDS[(1 + i) * 64 + l - 1] : pollLDS[2304 + 0 * 16 + i];
                    const float ri = (l < 63) ? pollLDS[(1 + i) * 64 + l + 1] : pollLDS[2304 + 1 * 16 + i];
                    const float nw = v + sA[i + 1] * (d - v) - sA[i] * (v - u)
                                       + sB[i][1] * (ri - v) - sB[i][0] * (v - le);
                    nv[i] = nw; s += nw;
                }
                s += __shfl_xor(s, 1); s += __shfl_xor(s, 2); s += __shfl_xor(s, 4);
                const float ratio = useRS ? (svS / (s * (1.0f / 64.0f) + EPSV)) : 1.0f;
                ringT[l] = nv[7] * ratio;
            } else if (w == 1) {   // bottom: rows 64..71
                #pragma unroll
                for (int i = 0; i < 8; ++i) sI[i] = pollLDS[576 + i * 64 + l];
                const float upr = botE[0][15][l >> 2][l & 3];
                const float dnr = pollLDS[576 + 8 * 64 + l];
                #pragma unroll
                for (int i = 0; i < 8; ++i) {
                    const float v = sI[i];
                    const float u = i ? sI[i - 1] : upr;
                    const float d = (i < 7) ? sI[i + 1] : dnr;
                    const float le = (l > 0)  ? pollLDS[576 + i * 64 + l - 1] : pollLDS[2304 + 2 * 16 + i];
                    const float ri = (l < 63) ? pollLDS[576 + i * 64 + l + 1] : pollLDS[2304 + 3 * 16 + i];
                    const float nw = v + sA[i + 1] * (d - v) - sA[i] * (v - u)
                                       + sB[i][1] * (ri - v) - sB[i][0] * (v - le);
                    nv[i] = nw; s += nw;
                }
                s += __shfl_xor(s, 1); s += __shfl_xor(s, 2); s += __shfl_xor(s, 4);
                const float ratio = useRS ? (svS / (s * (1.0f / 64.0f) + EPSV)) : 1.0f;
                ringB[l] = nv[0] * ratio;
            } else if (w == 2) {   // left: cols -8..-1, row l
                #pragma unroll
                for (int j = 0; j < 8; ++j) sI[j] = pollLDS[1152 + (1 + j) * 64 + l];
                const float lfr = pollLDS[1152 + l];
                const float rgr = lftE[0][l >> 2][0][l & 3];
                #pragma unroll
                for (int j = 0; j < 8; ++j) {
                    const float v = sI[j];
                    const float le = j ? sI[j - 1] : lfr;
                    const float ri = (j < 7) ? sI[j + 1] : rgr;
                    const float u = (l > 0)  ? pollLDS[1152 + (1 + j) * 64 + l - 1] : pollLDS[2304 + 0 * 16 + 8 + j];
                    const float d = (l < 63) ? pollLDS[1152 + (1 + j) * 64 + l + 1] : pollLDS[2304 + 2 * 16 + 8 + j];
                    const float nw = v + sA[j + 1] * (ri - v) - sA[j] * (v - le)
                                       + sB[j][1] * (d - v) - sB[j][0] * (v - u);
                    nv[j] = nw; s += nw;
                }
                s += __shfl_xor(s, 1); s += __shfl_xor(s, 2); s += __shfl_xor(s, 4);
                const float ratio = useRS ? (svS / (s * (1.0f / 64.0f) + EPSV)) : 1.0f;
                ringL[l] = nv[7] * ratio;
            } else {               // right: cols 64..71
                #pragma unroll
                for (int j = 0; j < 8; ++j) sI[j] = pollLDS[1728 + j * 64 + l];
                const float lfr = rgtE[0][l >> 2][15][l & 3];
                const float rgr = pollLDS[1728 + 8 * 64 + l];
                #pragma unroll
                for (int j = 0; j < 8; ++j) {
                    const float v = sI[j];
                    const float le = j ? sI[j - 1] : lfr;
                    const float ri = (j < 7) ? sI[j + 1] : rgr;
                    const float u = (l > 0)  ? pollLDS[1728 + j * 64 + l - 1] : pollLDS[2304 + 1 * 16 + 8 + j];
                    const float d = (l < 63) ? pollLDS[1728 + j * 64 + l + 1] : pollLDS[2304 + 3 * 16 + 8 + j];
                    const float nw = v + sA[j + 1] * (ri - v) - sA[j] * (v - le)
                                       + sB[j][1] * (d - v) - sB[j][0] * (v - u);
                    nv[j] = nw; s += nw;
                }
                s += __shfl_xor(s, 1); s += __shfl_xor(s, 2); s += __shfl_xor(s, 4);
                const float ratio = useRS ? (svS / (s * (1.0f / 64.0f) + EPSV)) : 1.0f;
                ringR[l] = nv[0] * ratio;
            }
        }
        __syncthreads();   // bar2: edges p1 + rings complete

        // ---- phase 2: step B (iter 2S+1 -> 2S+2), all intra-WG ----
        {
            float up[4], dn[4], lf[4], rg[4];
            if (ty > 0) {
                #pragma unroll
                for (int c = 0; c < 4; ++c) up[c] = botE[1][ty - 1][tx][c];
            } else if (eT) {
                #pragma unroll
                for (int c = 0; c < 4; ++c) up[c] = ringT[tx * 4 + c];
            } else { up[0] = up[1] = up[2] = up[3] = 0.0f; }
            if (ty < 15) {
                #pragma unroll
                for (int c = 0; c < 4; ++c) dn[c] = topE[1][ty + 1][tx][c];
            } else if (eB) {
                #pragma unroll
                for (int c = 0; c < 4; ++c) dn[c] = ringB[tx * 4 + c];
            } else { dn[0] = dn[1] = dn[2] = dn[3] = 0.0f; }
            if (tx > 0) {
                #pragma unroll
                for (int r = 0; r < 4; ++r) lf[r] = rgtE[1][ty][tx - 1][r];
            } else if (eL) {
                #pragma unroll
                for (int r = 0; r < 4; ++r) lf[r] = ringL[ty * 4 + r];
            } else { lf[0] = lf[1] = lf[2] = lf[3] = 0.0f; }
            if (tx < 15) {
                #pragma unroll
                for (int r = 0; r < 4; ++r) rg[r] = lftE[1][ty][tx + 1][r];
            } else if (eR) {
                #pragma unroll
                for (int r = 0; r < 4; ++r) rg[r] = ringR[ty * 4 + r];
            } else { rg[0] = rg[1] = rg[2] = rg[3] = 0.0f; }

            float s = 0.0f;
            float nv2[4][4];
            #pragma unroll
            for (int r = 0; r < 4; ++r) {
                #pragma unroll
                for (int c = 0; c < 4; ++c) {
                    const float v = I1[r][c];
                    const float u = r       ? I1[r - 1][c] : up[c];
                    const float d = (r < 3) ? I1[r + 1][c] : dn[c];
                    const float le = c      ? I1[r][c - 1] : lf[r];
                    const float ri = (c < 3) ? I1[r][c + 1] : rg[r];
                    const float t = cvaL[r + 1][c] * (d - v) - cvaL[r][c] * (v - u)
                                  + chaL[r][c + 1] * (ri - v) - chaL[r][c] * (v - le);
                    const float nw = v + t;
                    nv2[r][c] = nw; s += nw;
                }
            }
            s += __shfl_xor(s, 1);
            s += __shfl_xor(s, 16);
            const float ratio = useR ? (sv / (s * (1.0f / 64.0f) + EPSV)) : 1.0f;
            #pragma unroll
            for (int r = 0; r < 4; ++r) {
                #pragma unroll
                for (int c = 0; c < 4; ++c) I[r][c] = nv2[r][c] * ratio;
            }
        }
    }

    // ---- global completion barrier (protects p0 slots living in out_img region) ----
    __syncthreads();
    if (tid == 0) {
        __hip_atomic_fetch_add(cnt, 1, __ATOMIC_RELAXED, __HIP_MEMORY_SCOPE_AGENT);
        while (__hip_atomic_load(cnt, __ATOMIC_RELAXED, __HIP_MEMORY_SCOPE_AGENT) < 256)
            __builtin_amdgcn_s_sleep(1);
    }
    __syncthreads();

    // ---- final store; clear mantissa bit0 so replay leftovers never match a tag ----
    #pragma unroll
    for (int r = 0; r < 4; ++r) {
        float4 o;
        o.x = __uint_as_float(__float_as_uint(I[r][0]) & ~1u);
        o.y = __uint_as_float(__float_as_uint(I[r][1]) & ~1u);
        o.z = __uint_as_float(__float_as_uint(I[r][2]) & ~1u);
        o.w = __uint_as_float(__float_as_uint(I[r][3]) & ~1u);
        *(float4*)(out_img + ((size_t)b * HH + y0 + r) * WW + x0) = o;
    }
}

extern "C" void kernel_launch(void* const* d_in, const int* in_sizes, int n_in,
                              void* d_out, int out_size, void* d_ws, size_t ws_size,
                              hipStream_t stream) {
    const float* image  = (const float*)d_in[0];
    const float* source = (const float*)d_in[1];
    const float* mask   = (const float*)d_in[2];
    const float* ybic   = (const float*)d_in[3];
    const float* logk   = (const float*)d_in[4];

    float* out_img = (float*)d_out;                          // [B,1,H,W] (also parity-0 slots)
    float* out_cv  = out_img + (size_t)BB * HH * WW;         // [B,1,H-1,W]
    float* out_ch  = out_cv + (size_t)BB * (HH - 1) * WW;    // [B,1,H,W-1]

    unsigned* halo0 = (unsigned*)d_out;                      // parity 0: 2.36MB inside img region (4MB)
    unsigned* halo1 = (unsigned*)d_ws;                       // parity 1: 2.36MB in ws
    int* cnt = (int*)((char*)d_ws + 2359296);                // completion counter (64B line)

    (void)hipMemsetAsync(cnt, 0, 64, stream);

    int total = BB * HH * WW;
    prep_kernel<<<(total + 255) / 256, 256, 0, stream>>>(image, ybic, logk, out_cv, out_ch);

    dim3 grid(WW / 64, HH / 64, BB);
    persist_kernel<<<grid, 256, 0, stream>>>(ybic, out_img, out_cv, out_ch,
                                             source, mask, halo0, halo1, cnt);
}

// Round 11
// 226.060 us; speedup vs baseline: 1.9167x; 1.9167x over previous
//
#include <hip/hip_runtime.h>

#define HH 512
#define WW 512
#define BB 4
#define SH 64
#define SW 64
#define NPRE 128
#define LAMV 0.24f
#define EPSV 1e-8f

typedef unsigned long long u64;

// ---------------- prep: cv / ch edge weights (unchanged, verified) ----------------
__global__ __launch_bounds__(256) void prep_kernel(
    const float* __restrict__ image, const float* __restrict__ ybic,
    const float* __restrict__ logk,
    float* __restrict__ cv, float* __restrict__ ch)
{
    int idx = blockIdx.x * 256 + threadIdx.x;
    if (idx >= BB * HH * WW) return;
    int x = idx % WW;
    int y = (idx / WW) % HH;
    int b = idx / (WW * HH);

    float K = expf(logk[0]);
    float invK2 = 1.0f / (K * K);

    const float* img = image + (size_t)b * 3 * HH * WW;
    const float* yb  = ybic  + (size_t)b * HH * WW;

    float f0 = img[y * WW + x];
    float f1 = img[HH * WW + y * WW + x];
    float f2 = img[2 * HH * WW + y * WW + x];
    float f3 = yb[y * WW + x];

    if (y < HH - 1) {
        float s = fabsf(img[(y + 1) * WW + x] - f0)
                + fabsf(img[HH * WW + (y + 1) * WW + x] - f1)
                + fabsf(img[2 * HH * WW + (y + 1) * WW + x] - f2)
                + fabsf(yb[(y + 1) * WW + x] - f3);
        s *= 0.25f;
        cv[(size_t)b * (HH - 1) * WW + y * WW + x] = 1.0f / (1.0f + s * s * invK2);
    }
    if (x < WW - 1) {
        float s = fabsf(img[y * WW + x + 1] - f0)
                + fabsf(img[HH * WW + y * WW + x + 1] - f1)
                + fabsf(img[2 * HH * WW + y * WW + x + 1] - f2)
                + fabsf(yb[y * WW + x + 1] - f3);
        s *= 0.25f;
        ch[(size_t)b * HH * (WW - 1) + y * (WW - 1) + x] = 1.0f / (1.0f + s * s * invK2);
    }
}

// halo slot: [parity][edge][b][tileY][tileX][32 x u64]; edges 0=Top,1=Bot,2=Lft,3=Rgt
// Each u64 = {hiFloat, loFloat} with mantissa-LSB tags:
//   loFloat LSB = 1            (poison 0xAA.. has LSB 0 -> never matches)
//   hiFloat LSB = (gen>>1)&1   (alternates per reuse of a parity slot)
// 8B atomic store => tag+payload indivisible: ONE producer->consumer RT, no flags.
#define PSTRIDE (4 * BB * 64 * 32)   // u64 elements between parity 0 and 1

__device__ __forceinline__ u64* hslot0(u64* halo, int e, int b, int tY, int tX) {
    return halo + ((size_t)((e * BB + b) * 64 + tY * 8 + tX)) * 32;
}

__device__ __forceinline__ u64 pack2(float a, float b, unsigned phase) {
    unsigned ua = (__builtin_bit_cast(unsigned, a) & ~1u) | 1u;
    unsigned ub = (__builtin_bit_cast(unsigned, b) & ~1u) | phase;
    return ((u64)ub << 32) | ua;
}
__device__ __forceinline__ void st8(u64* p, u64 v) {
    __hip_atomic_store(p, v, __ATOMIC_RELAXED, __HIP_MEMORY_SCOPE_AGENT);
}
__device__ __forceinline__ u64 ld8(u64* p) {
    return __hip_atomic_load(p, __ATOMIC_RELAXED, __HIP_MEMORY_SCOPE_AGENT);
}
// check tags of one 16B edge; unpack on success
__device__ __forceinline__ bool chk2(u64 w0, u64 w1, unsigned phase, float out[4]) {
    unsigned l0 = (unsigned)w0, h0 = (unsigned)(w0 >> 32);
    unsigned l1 = (unsigned)w1, h1 = (unsigned)(w1 >> 32);
    if (((l0 & 1u) == 1u) & ((h0 & 1u) == phase) &
        ((l1 & 1u) == 1u) & ((h1 & 1u) == phase)) {
        out[0] = __builtin_bit_cast(float, l0);
        out[1] = __builtin_bit_cast(float, h0);
        out[2] = __builtin_bit_cast(float, l1);
        out[3] = __builtin_bit_cast(float, h1);
        return true;
    }
    return false;
}

// ---------------- persistent kernel: round-8 skeleton + drain-free barrier + pre-poll ----
// Grid (8,8,4) x 256 thr; thread = 4x4 px; WG = 64x64 tile. ONE raw barrier per
// iteration (lgkmcnt-only: publishes are fire-and-forget tagged stores; the
// __syncthreads vmcnt(0) drain was ~0.3-0.4us/iter of pure stall). Same-address
// publish ordering across parity reuse guaranteed by a loop-top vmcnt(0) that is
// free in steady state (queue empty since the previous compute phase).
__global__ __launch_bounds__(256) void persist_kernel(
    const float* __restrict__ ybic, float* __restrict__ out_img,
    const float* __restrict__ cv, const float* __restrict__ ch,
    const float* __restrict__ src, const float* __restrict__ mask,
    u64* __restrict__ halo)
{
    const int b = blockIdx.z, tileY = blockIdx.y, tileX = blockIdx.x;
    const int tid = threadIdx.x;
    const int tx = tid & 15, ty = tid >> 4;
    const int y0 = tileY * 64 + ty * 4, x0 = tileX * 64 + tx * 4;

    // ---- load state into registers (identical math to verified rounds) ----
    float I[4][4];
    #pragma unroll
    for (int r = 0; r < 4; ++r) {
        float4 t = *(const float4*)(ybic + ((size_t)b * HH + y0 + r) * WW + x0);
        I[r][0] = t.x; I[r][1] = t.y; I[r][2] = t.z; I[r][3] = t.w;
    }
    float cvaL[5][4];   // lambda * cv at interfaces y0-1 .. y0+3
    #pragma unroll
    for (int i = 0; i < 5; ++i) {
        int y = y0 - 1 + i;
        if (y >= 0 && y < HH - 1) {
            float4 t = *(const float4*)(cv + ((size_t)b * (HH - 1) + y) * WW + x0);
            cvaL[i][0] = t.x * LAMV; cvaL[i][1] = t.y * LAMV;
            cvaL[i][2] = t.z * LAMV; cvaL[i][3] = t.w * LAMV;
        } else {
            #pragma unroll
            for (int c = 0; c < 4; ++c) cvaL[i][c] = 0.0f;
        }
    }
    float chaL[4][5];   // lambda * ch at interfaces x0-1 .. x0+3
    #pragma unroll
    for (int r = 0; r < 4; ++r) {
        const float* row = ch + ((size_t)b * HH + y0 + r) * (WW - 1);
        #pragma unroll
        for (int j = 0; j < 5; ++j) {
            int x = x0 - 1 + j;
            chaL[r][j] = ((unsigned)x <= (unsigned)(WW - 2)) ? row[x] * LAMV : 0.0f;
        }
    }
    const size_t sidx = ((size_t)b * SH + (y0 >> 3)) * SW + (x0 >> 3);
    const float sv = src[sidx];
    const bool useR = (mask[sidx] >= 0.5f);

    // parity-double-buffered LDS edge exchange (intra-WG halo): 32 KB
    __shared__ float topE[2][16][16][4];
    __shared__ float botE[2][16][16][4];
    __shared__ float lftE[2][16][16][4];
    __shared__ float rgtE[2][16][16][4];

    // publish / poll roles (round-8, verified)
    const bool pubT = (ty == 0)  && (tileY > 0);
    const bool pubB = (ty == 15) && (tileY < 7);
    const bool pubL = (tx == 0)  && (tileX > 0);
    const bool pubR = (tx == 15) && (tileX < 7);
    const bool pollU = pubT, pollD = pubB, pollL = pubL, pollR = pubR;

    // precomputed parity-0 pointers (parity adds PSTRIDE); dummy = own top slot
    u64* dummy = hslot0(halo, 0, b, tileY, tileX) + tx * 2;
    u64* pTb = dummy;                                          // own top edge
    u64* pBb = hslot0(halo, 1, b, tileY, tileX) + tx * 2;
    u64* pLb = hslot0(halo, 2, b, tileY, tileX) + ty * 2;
    u64* pRb = hslot0(halo, 3, b, tileY, tileX) + ty * 2;
    u64* euB = pollU ? hslot0(halo, 1, b, tileY - 1, tileX) + tx * 2 : dummy;
    u64* edB = pollD ? hslot0(halo, 0, b, tileY + 1, tileX) + tx * 2 : dummy;
    u64* elB = pollL ? hslot0(halo, 3, b, tileY, tileX - 1) + ty * 2 : dummy;
    u64* erB = pollR ? hslot0(halo, 2, b, tileY, tileX + 1) + ty * 2 : dummy;

    // halo values; zeros persist for image-boundary lanes (never overwritten)
    float up[4] = {0, 0, 0, 0}, dn[4] = {0, 0, 0, 0};
    float lf[4] = {0, 0, 0, 0}, rg[4] = {0, 0, 0, 0};

    #pragma unroll 1
    for (int k = 0; k < NPRE; ++k) {
        const int p = k & 1;
        const unsigned gen = (unsigned)(k + 1);
        const unsigned phase = (gen >> 1) & 1u;
        const size_t po = (size_t)p * PSTRIDE;

        // ---- loop-top vmcnt(0): free in steady state (queue idle since compute),
        //      guarantees same-address publish ordering across parity reuse ----
        asm volatile("s_waitcnt vmcnt(0)" ::: "memory");

        // ---- global publishes (fire-and-forget tagged stores) ----
        if (pubT) {
            u64* e = pTb + po;
            st8(e + 0, pack2(I[0][0], I[0][1], phase));
            st8(e + 1, pack2(I[0][2], I[0][3], phase));
        }
        if (pubB) {
            u64* e = pBb + po;
            st8(e + 0, pack2(I[3][0], I[3][1], phase));
            st8(e + 1, pack2(I[3][2], I[3][3], phase));
        }
        if (pubL) {
            u64* e = pLb + po;
            st8(e + 0, pack2(I[0][0], I[1][0], phase));
            st8(e + 1, pack2(I[2][0], I[3][0], phase));
        }
        if (pubR) {
            u64* e = pRb + po;
            st8(e + 0, pack2(I[0][3], I[1][3], phase));
            st8(e + 1, pack2(I[2][3], I[3][3], phase));
        }

        // ---- pre-issue poll round 0 (latency hides under LDS publish + barrier) ----
        u64* eu = euB + po; u64* ed = edB + po;
        u64* el = elB + po; u64* er = erB + po;
        u64 A0 = ld8(eu + 0), A1 = ld8(eu + 1);
        u64 B0 = ld8(ed + 0), B1 = ld8(ed + 1);
        u64 C0 = ld8(el + 0), C1 = ld8(el + 1);
        u64 D0 = ld8(er + 0), D1 = ld8(er + 1);

        // ---- LDS publish (intra-WG halo) ----
        #pragma unroll
        for (int c = 0; c < 4; ++c) {
            topE[p][ty][tx][c] = I[0][c];
            botE[p][ty][tx][c] = I[3][c];
            lftE[p][ty][tx][c] = I[c][0];
            rgtE[p][ty][tx][c] = I[c][3];
        }
        // ---- raw barrier: LDS-ordering only, NO vmcnt drain ----
        asm volatile("s_waitcnt lgkmcnt(0)\n\ts_barrier" ::: "memory");

        // ---- gather intra-WG halos from LDS ----
        if (ty > 0) {
            #pragma unroll
            for (int c = 0; c < 4; ++c) up[c] = botE[p][ty - 1][tx][c];
        }
        if (ty < 15) {
            #pragma unroll
            for (int c = 0; c < 4; ++c) dn[c] = topE[p][ty + 1][tx][c];
        }
        if (tx > 0) {
            #pragma unroll
            for (int r = 0; r < 4; ++r) lf[r] = rgtE[p][ty][tx - 1][r];
        }
        if (tx < 15) {
            #pragma unroll
            for (int r = 0; r < 4; ++r) rg[r] = lftE[p][ty][tx + 1][r];
        }

        // ---- check pre-issued round, then fused concurrent re-poll on miss ----
        {
            bool du = !pollU, dd = !pollD, dl = !pollL, dr = !pollR;
            if (!du && chk2(A0, A1, phase, up)) du = true;
            if (!dd && chk2(B0, B1, phase, dn)) dd = true;
            if (!dl && chk2(C0, C1, phase, lf)) dl = true;
            if (!dr && chk2(D0, D1, phase, rg)) dr = true;
            while (!(du & dd & dl & dr)) {
                u64 a0 = ld8(eu + 0), a1 = ld8(eu + 1);
                u64 b0 = ld8(ed + 0), b1 = ld8(ed + 1);
                u64 c0 = ld8(el + 0), c1 = ld8(el + 1);
                u64 d0 = ld8(er + 0), d1 = ld8(er + 1);
                if (!du && chk2(a0, a1, phase, up)) du = true;
                if (!dd && chk2(b0, b1, phase, dn)) dd = true;
                if (!dl && chk2(c0, c1, phase, lf)) dl = true;
                if (!dr && chk2(d0, d1, phase, rg)) dr = true;
            }
        }

        // ---- diffuse + block mean + adjust (all registers) ----
        float nv[4][4];
        float s = 0.0f;
        #pragma unroll
        for (int r = 0; r < 4; ++r) {
            #pragma unroll
            for (int c = 0; c < 4; ++c) {
                const float v = I[r][c];
                const float u = r       ? I[r - 1][c] : up[c];
                const float d = (r < 3) ? I[r + 1][c] : dn[c];
                const float l = c       ? I[r][c - 1] : lf[r];
                const float g = (c < 3) ? I[r][c + 1] : rg[r];
                const float t = cvaL[r + 1][c] * (d - v)
                              - cvaL[r][c]     * (v - u)
                              + chaL[r][c + 1] * (g - v)
                              - chaL[r][c]     * (v - l);
                const float w = v + t;
                nv[r][c] = w;
                s += w;
            }
        }
        // 8x8 block = 2x2 thread group (lanes ^1 and ^16, same wave)
        s += __shfl_xor(s, 1);
        s += __shfl_xor(s, 16);
        const float mean  = s * (1.0f / 64.0f);
        const float ratio = useR ? (sv / (mean + EPSV)) : 1.0f;
        #pragma unroll
        for (int r = 0; r < 4; ++r)
            #pragma unroll
            for (int c = 0; c < 4; ++c) I[r][c] = nv[r][c] * ratio;
    }

    // ---- store final image ----
    #pragma unroll
    for (int r = 0; r < 4; ++r)
        *(float4*)(out_img + ((size_t)b * HH + y0 + r) * WW + x0) =
            make_float4(I[r][0], I[r][1], I[r][2], I[r][3]);
}

extern "C" void kernel_launch(void* const* d_in, const int* in_sizes, int n_in,
                              void* d_out, int out_size, void* d_ws, size_t ws_size,
                              hipStream_t stream) {
    const float* image  = (const float*)d_in[0];
    const float* source = (const float*)d_in[1];
    const float* mask   = (const float*)d_in[2];
    const float* ybic   = (const float*)d_in[3];
    const float* logk   = (const float*)d_in[4];

    float* out_img = (float*)d_out;                          // [B,1,H,W]
    float* out_cv  = out_img + (size_t)BB * HH * WW;         // [B,1,H-1,W]
    float* out_ch  = out_cv + (size_t)BB * (HH - 1) * WW;    // [B,1,H,W-1]

    u64* halo = (u64*)d_ws;   // 512 KB tagged edge slots; NO reset needed:
                              // poison LSB=0 never matches, phase bit kills stale gens

    int total = BB * HH * WW;
    prep_kernel<<<(total + 255) / 256, 256, 0, stream>>>(image, ybic, logk, out_cv, out_ch);

    dim3 grid(WW / 64, HH / 64, BB);
    persist_kernel<<<grid, 256, 0, stream>>>(ybic, out_img, out_cv, out_ch,
                                             source, mask, halo);
}